// Round 5
// baseline (114.398 us; speedup 1.0000x reference)
//
#include <hip/hip_runtime.h>
#include <hip/hip_fp16.h>
#include <cstdint>
#include <cstddef>

// z = soft_thresh(Toeplitz(v) @ x + W2 @ y, beta) -- complex, N=1024, M=256, B=1024
// Output = Re(z) only: [1024,1024] f32 (R4 finding).
//
// R23: Gauss 3-mult complex GEMM (R22) RESTRUCTURED back to 2 blocks/CU.
// R22 post-mortem: -25% work was canceled by dropping to 1 block/CU (lost the
// co-resident-block barrier-overlap R13 had; m114 mechanism). R23: 512 blocks
// x 256 thr (2/CU), 64x32 tile (16x32 grid), BK=64 as 2x32k half-slabs,
// proven 64B-row XOR swizzle, reg-staged 2-deep prefetch, 1 barrier/iter.
// No wave K-split: 4 waves = 2x2 quadrants (32m x 16n), full K per wave ->
// pure-register Gauss combine epilogue. LDS 36KB/buf x2 = 72KB <= 80KB/block.

#define BETA_F 0.01f
#define EPS_F  1e-12f
#define ASZ (1024 * 1280)

typedef __attribute__((ext_vector_type(8))) _Float16 half8;
typedef __attribute__((ext_vector_type(4))) _Float16 half4;
typedef __attribute__((ext_vector_type(4))) float   floatx4;

__device__ alignas(16) _Float16 g_A[3 * ASZ];     // 7.86 MB: A1,A2,A3
__device__ alignas(16) _Float16 g_B[3 * ASZ];     // 7.86 MB: B1t,B2t,B3t

// ---------------- prep: build A1/A2/A3 and B1t/B2t/B3t -----------------------
__global__ __launch_bounds__(256) void build_all(
    const float* __restrict__ v_re, const float* __restrict__ v_im,
    const float* __restrict__ W2_re, const float* __restrict__ W2_im,
    const float* __restrict__ x_re, const float* __restrict__ x_im,
    const float* __restrict__ y_re, const float* __restrict__ y_im)
{
    const int bx = blockIdx.x;
    if (bx < 640) {                            // A-part: 1024x1280 / 8 per thread
        int t = bx * 256 + threadIdx.x;
        int i  = t / 160;
        int c  = t - i * 160;
        int kp = c * 8;                        // 0..1272, segment-aligned
        half8 h1, h2, h3;
        if (kp < 1024) {                       // Toeplitz zone
#pragma unroll
            for (int j = 0; j < 8; ++j) {
                float a = v_re[1023 + i - kp - j];
                float b = v_im[1023 + i - kp - j];
                h1[j] = (_Float16)a;
                h2[j] = (_Float16)b;
                h3[j] = (_Float16)(a + b);
            }
        } else {                               // W2 zone
            const float* sa = W2_re + i * 256 + (kp - 1024);
            const float* sb = W2_im + i * 256 + (kp - 1024);
#pragma unroll
            for (int j = 0; j < 8; ++j) {
                float a = sa[j], b = sb[j];
                h1[j] = (_Float16)a;
                h2[j] = (_Float16)b;
                h3[j] = (_Float16)(a + b);
            }
        }
        size_t base = (size_t)i * 1280 + kp;
        *reinterpret_cast<half8*>(g_A + base)           = h1;
        *reinterpret_cast<half8*>(g_A + ASZ + base)     = h2;
        *reinterpret_cast<half8*>(g_A + 2 * ASZ + base) = h3;
        return;
    }
    // B-part: transpose x/y 32x32 tiles -> B*t[n][k]
    __shared__ float lre[32][33];
    __shared__ float lim[32][33];
    int idx = bx - 640;                        // 0..1279
    int bk  = idx % 40;                        // k-tile (0..31 x, 32..39 y)
    int by  = idx / 40;                        // n-tile
    const float* sre = (bk < 32) ? x_re : y_re;
    const float* sim = (bk < 32) ? x_im : y_im;
    int krow0  = (bk < 32) ? bk * 32 : (bk - 32) * 32;     // row in source
    int kglob0 = (bk < 32) ? bk * 32 : 1024 + (bk - 32) * 32;
    int n0 = by * 32;
    int tid = threadIdx.x;
    {   // float4-vectorized staging
        int kk  = tid >> 3;                    // 0..31
        int tx4 = (tid & 7) * 4;
        const floatx4 re4 = *reinterpret_cast<const floatx4*>(
            sre + (size_t)(krow0 + kk) * 1024 + n0 + tx4);
        const floatx4 im4 = *reinterpret_cast<const floatx4*>(
            sim + (size_t)(krow0 + kk) * 1024 + n0 + tx4);
#pragma unroll
        for (int j = 0; j < 4; ++j) {
            lre[kk][tx4 + j] = re4[j];
            lim[kk][tx4 + j] = im4[j];
        }
    }
    __syncthreads();
    int lane_n = tid >> 3;                     // 0..31
    int kq     = (tid & 7) * 4;                // 0..28
    half4 h1, h2, h3;
#pragma unroll
    for (int j = 0; j < 4; ++j) {
        float re = lre[kq + j][lane_n];
        float im = lim[kq + j][lane_n];
        h1[j] = (_Float16)re;
        h2[j] = (_Float16)im;
        h3[j] = (_Float16)(re + im);
    }
    size_t base = (size_t)(n0 + lane_n) * 1280 + kglob0 + kq;
    *reinterpret_cast<half4*>(g_B + base)           = h1;
    *reinterpret_cast<half4*>(g_B + ASZ + base)     = h2;
    *reinterpret_cast<half4*>(g_B + 2 * ASZ + base) = h3;
}

// ---------------- Gauss GEMM + fused soft-threshold --------------------------
// 512 blocks (2/CU), 256 threads (4 waves = 2x2 quadrants of 32m x 16n).
// Tile 64m x 32n, K=1280, BK=64 (2 x 32k half-slabs, 64B rows, XOR swizzle).
// LDS/buf: A 3x8KB + B 3x4KB = 36KB; dbuf 72KB. NIT=20, 1 barrier/iter,
// 2-deep register prefetch. Per wave/iter: 3 products x (6 ds_read + 4 MFMA).
__global__ __launch_bounds__(256, 2) void gemm_fused(float* __restrict__ out,
                                                     int out_n)
{
    __shared__ __align__(16) char smem[73728];   // 2 x 36864

    const int tid  = threadIdx.x;
    const int lane = tid & 63;
    const int w    = tid >> 6;          // 0..3
    const int wn   = w & 1;             // n half (16 cols)
    const int wm   = w >> 1;            // m half (32 rows)

    const int bid = blockIdx.x;         // 0..511
    const int xcd = bid & 7;
    const int t   = bid >> 3;           // 0..63
    const int mi0 = ((xcd & 1) * 8 + (t & 7)) * 64;    // 16 row-tiles
    const int ni0 = ((xcd >> 1) * 8 + (t >> 3)) * 32;  // 32 col-tiles

    floatx4 acc[3][2];                  // [product][mi]
#pragma unroll
    for (int p = 0; p < 3; ++p)
#pragma unroll
        for (int a = 0; a < 2; ++a) acc[p][a] = (floatx4)0.0f;

    // --- staging maps (16B chunks, 64B half-rows, proven XOR swizzle) -------
    // A: 3 slabs x [2 kh][64 rows][64B]; thread does (rSA, jjA) for each p,kh2.
    const int rSA = tid >> 2;           // 0..63
    const int jjA = tid & 3;
    const int s0A = ((rSA & 15) >> 1) & 3;
    const int aOff = rSA * 64 + ((jjA ^ s0A) * 16);   // + buf*36864 + p*8192 + kh2*4096
    const _Float16* gA = g_A + (size_t)(mi0 + rSA) * 1280 + jjA * 8;

    // B: 3 slabs x [2 kh][32 rows][64B]; thread does (rSB, khB, jjB) per p.
    const int rSB = tid >> 3;           // 0..31
    const int j8b = tid & 7;
    const int khB = j8b >> 2;
    const int jjB = j8b & 3;
    const int s0B = ((rSB & 15) >> 1) & 3;
    const int bOff = 24576 + khB * 2048 + rSB * 64 + ((jjB ^ s0B) * 16);  // + buf*36864 + p*4096
    const _Float16* gB = g_B + (size_t)(ni0 + rSB) * 1280 + khB * 32 + jjB * 8;

    const int rowA = lane & 15;
    const int q    = lane >> 4;
    const int coff = (q ^ ((rowA >> 1) & 3)) * 16;

    const int NIT = 1280 / 64;          // 20

    // 2-deep prefetch: set[(kt+1)&1] holds slab kt+1 during iter kt
    half8 sA[2][3][2], sB[2][3];

    {   // prologue: slab 0 -> LDS buf 0 via temps; slab 1 -> set[1]
        half8 tA[3][2], tB[3];
#pragma unroll
        for (int p = 0; p < 3; ++p) {
#pragma unroll
            for (int kh2 = 0; kh2 < 2; ++kh2)
                tA[p][kh2] = *reinterpret_cast<const half8*>(
                    gA + (size_t)p * ASZ + kh2 * 32);
            tB[p] = *reinterpret_cast<const half8*>(gB + (size_t)p * ASZ);
        }
#pragma unroll
        for (int p = 0; p < 3; ++p) {
#pragma unroll
            for (int kh2 = 0; kh2 < 2; ++kh2)
                sA[1][p][kh2] = *reinterpret_cast<const half8*>(
                    gA + (size_t)p * ASZ + 64 + kh2 * 32);
            sB[1][p] = *reinterpret_cast<const half8*>(gB + (size_t)p * ASZ + 64);
        }
#pragma unroll
        for (int p = 0; p < 3; ++p) {
#pragma unroll
            for (int kh2 = 0; kh2 < 2; ++kh2)
                *reinterpret_cast<half8*>(smem + p * 8192 + kh2 * 4096 + aOff)
                    = tA[p][kh2];
            *reinterpret_cast<half8*>(smem + p * 4096 + bOff) = tB[p];
        }
    }
    __syncthreads();

#pragma unroll 2
    for (int kt = 0; kt < NIT; ++kt) {
        const int cur = kt & 1;
        const int nxt = cur ^ 1;
        if (kt + 2 < NIT) {             // issue slab kt+2 into set[cur]
#pragma unroll
            for (int p = 0; p < 3; ++p) {
#pragma unroll
                for (int kh2 = 0; kh2 < 2; ++kh2)
                    sA[cur][p][kh2] = *reinterpret_cast<const half8*>(
                        gA + (size_t)p * ASZ + (size_t)(kt + 2) * 64 + kh2 * 32);
                sB[cur][p] = *reinterpret_cast<const half8*>(
                    gB + (size_t)p * ASZ + (size_t)(kt + 2) * 64);
            }
        }
        const char* base = smem + cur * 36864;
#pragma unroll
        for (int p = 0; p < 3; ++p) {
            half8 bf[2], af[2][2];
#pragma unroll
            for (int kk = 0; kk < 2; ++kk)
                bf[kk] = *reinterpret_cast<const half8*>(
                    base + 24576 + p * 4096 + kk * 2048
                    + (wn * 16 + rowA) * 64 + coff);
#pragma unroll
            for (int kk = 0; kk < 2; ++kk)
#pragma unroll
                for (int mi = 0; mi < 2; ++mi)
                    af[kk][mi] = *reinterpret_cast<const half8*>(
                        base + p * 8192 + kk * 4096
                        + (wm * 32 + mi * 16 + rowA) * 64 + coff);
#pragma unroll
            for (int kk = 0; kk < 2; ++kk)
#pragma unroll
                for (int mi = 0; mi < 2; ++mi)
                    acc[p][mi] = __builtin_amdgcn_mfma_f32_16x16x32_f16(
                        af[kk][mi], bf[kk], acc[p][mi], 0, 0, 0);
        }
        if (kt + 1 < NIT) {             // store slab kt+1 (loaded >=1 iter ago)
            char* wb = smem + nxt * 36864;
#pragma unroll
            for (int p = 0; p < 3; ++p) {
#pragma unroll
                for (int kh2 = 0; kh2 < 2; ++kh2)
                    *reinterpret_cast<half8*>(wb + p * 8192 + kh2 * 4096 + aOff)
                        = sA[nxt][p][kh2];
                *reinterpret_cast<half8*>(wb + p * 4096 + bOff) = sB[nxt][p];
            }
        }
        __syncthreads();                // single barrier per iter
    }

    // ---- pure-register Gauss combine + soft-threshold epilogue --------------
    // C/D frag map: col=lane&15, row=(lane>>4)*4+r.  Re,Im in same lane.
    const int colL  = lane & 15;
    const int rquad = (lane >> 4) * 4;
#pragma unroll
    for (int mi = 0; mi < 2; ++mi)
#pragma unroll
        for (int r = 0; r < 4; ++r) {
            float m0 = acc[0][mi][r];
            float m1 = acc[1][mi][r];
            float m2 = acc[2][mi][r];
            float re = m0 - m1;
            float im = m2 - m0 - m1;
            float mag = sqrtf(re * re + im * im);
            float s = fmaxf(mag - BETA_F, 0.0f) / fmaxf(mag, EPS_F);
            int row = mi0 + wm * 32 + mi * 16 + rquad + r;
            int col = ni0 + wn * 16 + colL;
            size_t o = (size_t)row * 1024 + col;
            if (o < (size_t)out_n) out[o] = re * s;
        }
}

// ---------------- launcher ---------------------------------------------------
extern "C" void kernel_launch(void* const* d_in, const int* in_sizes, int n_in,
                              void* d_out, int out_size, void* d_ws, size_t ws_size,
                              hipStream_t stream) {
    (void)d_ws; (void)ws_size; (void)in_sizes; (void)n_in;
    const float* v_re  = (const float*)d_in[0];
    const float* v_im  = (const float*)d_in[1];
    const float* W2_re = (const float*)d_in[2];
    const float* W2_im = (const float*)d_in[3];
    const float* x_re  = (const float*)d_in[4];
    const float* x_im  = (const float*)d_in[5];
    const float* y_re  = (const float*)d_in[6];
    const float* y_im  = (const float*)d_in[7];
    float* out = (float*)d_out;

    build_all<<<1920, 256, 0, stream>>>(v_re, v_im, W2_re, W2_im,
                                        x_re, x_im, y_re, y_im);
    gemm_fused<<<512, 256, 0, stream>>>(out, out_size);
}